// Round 10
// baseline (307.490 us; speedup 1.0000x reference)
//
#include <hip/hip_runtime.h>
#include <hip/hip_bf16.h>

#define NN 8192
#define NE 262144

typedef float v2 __attribute__((ext_vector_type(2)));
typedef float v4 __attribute__((ext_vector_type(4)));
typedef float f4 __attribute__((ext_vector_type(4)));
typedef _Float16 h8 __attribute__((ext_vector_type(8)));
typedef _Float16 h4 __attribute__((ext_vector_type(4)));

__device__ __forceinline__ float rcp_(float x) { return __builtin_amdgcn_rcpf(x); }
__device__ __forceinline__ float sigm(float x) { return rcp_(1.0f + __expf(-x)); }
__device__ __forceinline__ float tanh_(float x) { return 1.0f - 2.0f * rcp_(__expf(2.0f * x) + 1.0f); }

// ---------------- merged prep: LSTM weights + dyn->f16 + degree count + GCN gemm1 (f16 out) ----------------
__global__ void k_prep_all(const float* __restrict__ dyn,
                           const float* __restrict__ wih0, const float* __restrict__ whh0,
                           const float* __restrict__ bih0, const float* __restrict__ bhh0,
                           const float* __restrict__ wih1, const float* __restrict__ whh1,
                           const float* __restrict__ bih1, const float* __restrict__ bhh1,
                           const int* __restrict__ dst,
                           const float* __restrict__ xs_, const float* __restrict__ g1w,
                           _Float16* __restrict__ dyn16, _Float16* __restrict__ WB0h,
                           _Float16* __restrict__ TLg, _Float16* __restrict__ WB1,
                           float* __restrict__ bias, int* __restrict__ cnt,
                           _Float16* __restrict__ hs_raw) {
    int b = blockIdx.x, tid = threadIdx.x;
    if (b < 4096) {
        int i = b * 256 + tid;
        f4 v = *(const f4*)(dyn + (size_t)i * 4);
        h4 o = {(_Float16)v[0], (_Float16)v[1], (_Float16)v[2], (_Float16)v[3]};
        *(h4*)(dyn16 + (size_t)i * 4) = o;
    } else if (b < 4900) {
        int i = (b - 4096) * 256 + tid;  // < 205824 exactly
        if (i < 65536) {
            int idx = i & 7, col = (i >> 3) & 511, kgq = (i >> 12) & 3, kt = i >> 14;
            int kh = kt * 32 + kgq * 8 + idx;
            WB0h[i] = (_Float16)whh0[col * 128 + kh];
        } else if (i < 73728) {
            int m = i - 65536;
            int kd = m & 15, g = m >> 4;
            TLg[m] = (_Float16)wih0[g * 16 + kd];
        } else if (i < 204800) {
            int m = i - 73728;
            int kt = m >> 14, rem = m & 16383, g = rem >> 5, kk = rem & 31, k = kt * 32 + kk;
            WB1[m] = (_Float16)((k < 128) ? wih1[g * 128 + k] : whh1[g * 128 + (k - 128)]);
        } else {
            int g = i - 204800;
            bias[g] = (g < 512) ? (bih0[g] + bhh0[g]) : (bih1[g - 512] + bhh1[g - 512]);
        }
    } else if (b < 5924) {
        int e = (b - 4900) * 256 + tid;
        if (e < NE) atomicAdd(&cnt[dst[e]], 1);
    } else {
        int wv = tid >> 6, ln = tid & 63;
        int row = (b - 5924) * 4 + wv;
        const float* xp = xs_ + (size_t)row * 128;
        float a = 0.f;
#pragma unroll 4
        for (int k = 0; k < 128; ++k) a += xp[k] * g1w[k * 64 + ln];
        hs_raw[(size_t)row * 64 + ln] = (_Float16)a;
    }
}

// ---------------- GCN: CSR build ----------------
__global__ __launch_bounds__(1024) void k_scan(const int* __restrict__ cnt, int* __restrict__ rowstart,
                                               float* __restrict__ dis) {
    __shared__ int part[1024];
    int t = threadIdx.x;
    int base = t * 8, s = 0, loc[8];
#pragma unroll
    for (int i = 0; i < 8; ++i) { loc[i] = s; s += cnt[base + i]; }
    part[t] = s;
    __syncthreads();
    for (int off = 1; off < 1024; off <<= 1) {
        int v = part[t];
        int add = (t >= off) ? part[t - off] : 0;
        __syncthreads();
        part[t] = v + add;
        __syncthreads();
    }
    int pre = (t == 0) ? 0 : part[t - 1];
#pragma unroll
    for (int i = 0; i < 8; ++i) {
        rowstart[base + i] = pre + loc[i];
        dis[base + i] = rsqrtf((float)(cnt[base + i] + 1));
    }
    if (t == 1023) rowstart[8192] = NE;
}
__global__ void k_fill(const int* __restrict__ src, const int* __restrict__ dst,
                       const int* __restrict__ rowstart, int* __restrict__ cursor,
                       int* __restrict__ srcidx) {
    int e = blockIdx.x * 256 + threadIdx.x;
    if (e < NE) {
        int d = dst[e];
        int pos = rowstart[d] + atomicAdd(&cursor[d], 1);
        srcidx[pos] = src[e];
    }
}
// gather layer1 (dis per-source) + BN/ReLU + fused layer-2 GEMM -> hs2 (f16)
__global__ __launch_bounds__(256) void k_gather_gemm(const _Float16* __restrict__ hs, const int* __restrict__ srcidx,
                                                     const int* __restrict__ rowstart, const float* __restrict__ dis,
                                                     const float* __restrict__ gb, const float* __restrict__ bng,
                                                     const float* __restrict__ bnb, const float* __restrict__ g2w,
                                                     _Float16* __restrict__ hs2) {
    int ln = threadIdx.x & 63;
    int d = (blockIdx.x * 256 + threadIdx.x) >> 6;
    float dd = dis[d];
    float acc = (float)hs[(size_t)d * 64 + ln] * dd;
    int b = rowstart[d], e = rowstart[d + 1];
    int i = b;
    for (; i + 4 <= e; i += 4) {
        int s0 = srcidx[i], s1 = srcidx[i + 1], s2 = srcidx[i + 2], s3 = srcidx[i + 3];
        acc += (float)hs[(size_t)s0 * 64 + ln] * dis[s0];
        acc += (float)hs[(size_t)s1 * 64 + ln] * dis[s1];
        acc += (float)hs[(size_t)s2 * 64 + ln] * dis[s2];
        acc += (float)hs[(size_t)s3 * 64 + ln] * dis[s3];
    }
    for (; i < e; ++i) { int s = srcidx[i]; acc += (float)hs[(size_t)s * 64 + ln] * dis[s]; }
    float rs = rsqrtf(1.0f + 1e-5f);
    float y = acc * dd + gb[ln];
    y = fmaxf(y * (bng[ln] * rs) + bnb[ln], 0.f);
    float a2 = 0.f;
#pragma unroll 8
    for (int k = 0; k < 64; ++k) a2 += __shfl(y, k, 64) * g2w[k * 64 + ln];
    hs2[(size_t)d * 64 + ln] = (_Float16)a2;
}
__global__ __launch_bounds__(256) void k_gather(const _Float16* __restrict__ hs, const int* __restrict__ srcidx,
                                                const int* __restrict__ rowstart, const float* __restrict__ dis,
                                                const float* __restrict__ gb, const float* __restrict__ bng,
                                                const float* __restrict__ bnb, float* __restrict__ out) {
    int ln = threadIdx.x & 63;
    int d = (blockIdx.x * 256 + threadIdx.x) >> 6;
    float dd = dis[d];
    float acc = (float)hs[(size_t)d * 64 + ln] * dd;
    int b = rowstart[d], e = rowstart[d + 1];
    int i = b;
    for (; i + 4 <= e; i += 4) {
        int s0 = srcidx[i], s1 = srcidx[i + 1], s2 = srcidx[i + 2], s3 = srcidx[i + 3];
        acc += (float)hs[(size_t)s0 * 64 + ln] * dis[s0];
        acc += (float)hs[(size_t)s1 * 64 + ln] * dis[s1];
        acc += (float)hs[(size_t)s2 * 64 + ln] * dis[s2];
        acc += (float)hs[(size_t)s3 * 64 + ln] * dis[s3];
    }
    for (; i < e; ++i) { int s = srcidx[i]; acc += (float)hs[(size_t)s * 64 + ln] * dis[s]; }
    float rs = rsqrtf(1.0f + 1e-5f);
    float v = acc * dd + gb[ln];
    v = v * (bng[ln] * rs) + bnb[ln];
    out[(size_t)d * 64 + ln] = fmaxf(v, 0.f);
}

// ---------------- fused 2-layer LSTM: EXACT round-5 form (198 us measured) ----------------
__device__ __forceinline__ h8 ldx(const _Float16* xs, int buf, int row, int chunk) {
    return *(const h8*)((const char*)xs + buf * 16384 + row * 512 + ((chunk ^ (row & 7)) << 4));
}
__device__ __forceinline__ void wrx(_Float16* xs, int buf, int row, int col, _Float16 v) {
    *(_Float16*)((char*)xs + buf * 16384 + row * 512 + ((((col >> 3) ^ (row & 7))) << 4) + (col & 7) * 2) = v;
}

__global__ __launch_bounds__(512, 2) void k_lstm(const _Float16* __restrict__ dyn16,
                                                 const _Float16* __restrict__ WB0h,
                                                 const _Float16* __restrict__ TLg,
                                                 const _Float16* __restrict__ WB1,
                                                 const float* __restrict__ bias,
                                                 float* __restrict__ rnn) {
    __shared__ __align__(16) _Float16 wb0[65536];  // W_hh0, 128 KB
    __shared__ __align__(16) _Float16 xs[16384];   // 2 bufs x 32 rows x [h0|h1], swizzled

    const int tid = threadIdx.x;
    const int wv = tid >> 6, ln = tid & 63;
    const int lr = ln & 15, kg = ln >> 4;
    const int j = wv * 16 + lr;
    const int row0 = blockIdx.x * 32;

    for (int i = tid; i < 8192; i += 512) ((v4*)wb0)[i] = ((const v4*)WB0h)[i];
    for (int i = tid; i < 16384; i += 512) xs[i] = (_Float16)0.f;

    h8 b1r[8][4];
#pragma unroll
    for (int kt = 0; kt < 8; ++kt)
#pragma unroll
        for (int q = 0; q < 4; ++q)
            b1r[kt][q] = *(const h8*)(WB1 + (size_t)kt * 16384 + (q * 128 + j) * 32 + kg * 8);
    h8 bt[4];
#pragma unroll
    for (int q = 0; q < 4; ++q)
        bt[q] = *(const h8*)(TLg + (q * 128 + j) * 16 + (kg & 1) * 8);

    float b0q[4], b1q[4];
#pragma unroll
    for (int q = 0; q < 4; ++q) { b0q[q] = bias[q * 128 + j]; b1q[q] = bias[512 + q * 128 + j]; }
    float c0[2][4], c1[2][4];
#pragma unroll
    for (int mt = 0; mt < 2; ++mt)
#pragma unroll
        for (int r = 0; r < 4; ++r) { c0[mt][r] = 0.f; c1[mt][r] = 0.f; }

    h8 dreg[2];
#pragma unroll
    for (int mt = 0; mt < 2; ++mt)
#pragma unroll
        for (int e = 0; e < 8; ++e) dreg[mt][e] = (_Float16)0.f;
    if (kg < 2) {
#pragma unroll
        for (int mt = 0; mt < 2; ++mt)
            dreg[mt] = *(const h8*)(dyn16 + (size_t)(row0 + mt * 16 + lr) * 512 + (kg & 1) * 8);
    }
    __syncthreads();  // wb0 + xs zero init visible

    // ===== prologue: step 0, layer 0 (h0(-1)=0 -> only dyn tail) =====
    {
        f4 acc[2][4];
#pragma unroll
        for (int q = 0; q < 4; ++q) { f4 z = {b0q[q], b0q[q], b0q[q], b0q[q]}; acc[0][q] = z; acc[1][q] = z; }
#pragma unroll
        for (int q = 0; q < 4; ++q) {
            acc[0][q] = __builtin_amdgcn_mfma_f32_16x16x32_f16(dreg[0], bt[q], acc[0][q], 0, 0, 0);
            acc[1][q] = __builtin_amdgcn_mfma_f32_16x16x32_f16(dreg[1], bt[q], acc[1][q], 0, 0, 0);
        }
#pragma unroll
        for (int mt = 0; mt < 2; ++mt)
#pragma unroll
            for (int r = 0; r < 4; ++r) {
                float iv = acc[mt][0][r], fv = acc[mt][1][r], gv = acc[mt][2][r], ov = acc[mt][3][r];
                float c = sigm(fv) * c0[mt][r] + sigm(iv) * tanh_(gv);
                c0[mt][r] = c;
                wrx(xs, 0, mt * 16 + kg * 4 + r, j, (_Float16)(sigm(ov) * tanh_(c)));
            }
        if (kg < 2) {  // dreg <- dyn(1)
#pragma unroll
            for (int mt = 0; mt < 2; ++mt)
                dreg[mt] = *(const h8*)(dyn16 + (size_t)(row0 + mt * 16 + lr) * 512 + 16 + (kg & 1) * 8);
        }
    }

#pragma unroll 1
    for (int i = 0; i < 31; ++i) {
        const int cur = i & 1, old = cur ^ 1;
        __syncthreads();  // h0(i) visible
        f4 acc[2][4];
        // ===== G1(i): K=256 = [h0(i) buf cur | h1(i-1) buf old] =====
#pragma unroll
        for (int q = 0; q < 4; ++q) { f4 z = {b1q[q], b1q[q], b1q[q], b1q[q]}; acc[0][q] = z; acc[1][q] = z; }
#pragma unroll
        for (int kt = 0; kt < 8; ++kt) {
            const int bufA = (kt < 4) ? cur : old;
            const int ch = (kt < 4) ? (kt * 4 + kg) : (16 + (kt - 4) * 4 + kg);
            h8 a0 = ldx(xs, bufA, lr, ch);
            h8 a1 = ldx(xs, bufA, 16 + lr, ch);
#pragma unroll
            for (int q = 0; q < 4; ++q) {
                acc[0][q] = __builtin_amdgcn_mfma_f32_16x16x32_f16(a0, b1r[kt][q], acc[0][q], 0, 0, 0);
                acc[1][q] = __builtin_amdgcn_mfma_f32_16x16x32_f16(a1, b1r[kt][q], acc[1][q], 0, 0, 0);
            }
        }
        // ===== EW1(i) -> h1(i) into buf cur =====
#pragma unroll
        for (int mt = 0; mt < 2; ++mt)
#pragma unroll
            for (int r = 0; r < 4; ++r) {
                float iv = acc[mt][0][r], fv = acc[mt][1][r], gv = acc[mt][2][r], ov = acc[mt][3][r];
                float c = sigm(fv) * c1[mt][r] + sigm(iv) * tanh_(gv);
                c1[mt][r] = c;
                wrx(xs, cur, mt * 16 + kg * 4 + r, 128 + j, (_Float16)(sigm(ov) * tanh_(c)));
            }
        // ===== G0(i+1): K = [h0(i) buf cur 128 | dyn(i+1) 16 | pad 16] =====
#pragma unroll
        for (int q = 0; q < 4; ++q) { f4 z = {b0q[q], b0q[q], b0q[q], b0q[q]}; acc[0][q] = z; acc[1][q] = z; }
#pragma unroll
        for (int kt = 0; kt < 4; ++kt) {
            h8 a0 = ldx(xs, cur, lr, kt * 4 + kg);
            h8 a1 = ldx(xs, cur, 16 + lr, kt * 4 + kg);
            h8 bq[4];
#pragma unroll
            for (int q = 0; q < 4; ++q)
                bq[q] = *(const h8*)(wb0 + (size_t)(((kt * 4 + kg) * 512 + q * 128 + j) * 8));
#pragma unroll
            for (int q = 0; q < 4; ++q) {
                acc[0][q] = __builtin_amdgcn_mfma_f32_16x16x32_f16(a0, bq[q], acc[0][q], 0, 0, 0);
                acc[1][q] = __builtin_amdgcn_mfma_f32_16x16x32_f16(a1, bq[q], acc[1][q], 0, 0, 0);
            }
        }
#pragma unroll
        for (int q = 0; q < 4; ++q) {
            acc[0][q] = __builtin_amdgcn_mfma_f32_16x16x32_f16(dreg[0], bt[q], acc[0][q], 0, 0, 0);
            acc[1][q] = __builtin_amdgcn_mfma_f32_16x16x32_f16(dreg[1], bt[q], acc[1][q], 0, 0, 0);
        }
        // ===== EW0(i+1) -> h0(i+1) into buf old =====
#pragma unroll
        for (int mt = 0; mt < 2; ++mt)
#pragma unroll
            for (int r = 0; r < 4; ++r) {
                float iv = acc[mt][0][r], fv = acc[mt][1][r], gv = acc[mt][2][r], ov = acc[mt][3][r];
                float c = sigm(fv) * c0[mt][r] + sigm(iv) * tanh_(gv);
                c0[mt][r] = c;
                wrx(xs, old, mt * 16 + kg * 4 + r, j, (_Float16)(sigm(ov) * tanh_(c)));
            }
        if (i < 30 && kg < 2) {  // prefetch dyn(i+2) (R5 placement)
#pragma unroll
            for (int mt = 0; mt < 2; ++mt)
                dreg[mt] = *(const h8*)(dyn16 + (size_t)(row0 + mt * 16 + lr) * 512 + (i + 2) * 16 + (kg & 1) * 8);
        }
    }
    __syncthreads();  // h0(31) visible
    // ===== epilogue: G1(31) + EW1(31) -> rnn =====
    {
        const int cur = 1, old = 0;
        f4 acc[2][4];
#pragma unroll
        for (int q = 0; q < 4; ++q) { f4 z = {b1q[q], b1q[q], b1q[q], b1q[q]}; acc[0][q] = z; acc[1][q] = z; }
#pragma unroll
        for (int kt = 0; kt < 8; ++kt) {
            const int bufA = (kt < 4) ? cur : old;
            const int ch = (kt < 4) ? (kt * 4 + kg) : (16 + (kt - 4) * 4 + kg);
            h8 a0 = ldx(xs, bufA, lr, ch);
            h8 a1 = ldx(xs, bufA, 16 + lr, ch);
#pragma unroll
            for (int q = 0; q < 4; ++q) {
                acc[0][q] = __builtin_amdgcn_mfma_f32_16x16x32_f16(a0, b1r[kt][q], acc[0][q], 0, 0, 0);
                acc[1][q] = __builtin_amdgcn_mfma_f32_16x16x32_f16(a1, b1r[kt][q], acc[1][q], 0, 0, 0);
            }
        }
#pragma unroll
        for (int mt = 0; mt < 2; ++mt)
#pragma unroll
            for (int r = 0; r < 4; ++r) {
                float iv = acc[mt][0][r], fv = acc[mt][1][r], gv = acc[mt][2][r], ov = acc[mt][3][r];
                float c = sigm(fv) * c1[mt][r] + sigm(iv) * tanh_(gv);
                float h = sigm(ov) * tanh_(c);
                rnn[(size_t)(row0 + mt * 16 + kg * 4 + r) * 128 + j] = h;
            }
    }
}

// ---------------- head: 128 blocks x 64 rows (minimize fc1w re-reads: 12.6 MB total) ----------------
__global__ __launch_bounds__(256) void k_head(const float* __restrict__ gnn, const float* __restrict__ rnn,
                                              const float* __restrict__ fc1w, const float* __restrict__ fc1b,
                                              const float* __restrict__ fbng, const float* __restrict__ fbnb,
                                              const float* __restrict__ fc2w, const float* __restrict__ fc2b,
                                              const float* __restrict__ outw, const float* __restrict__ outb,
                                              float* __restrict__ out) {
    __shared__ __align__(16) float xin[64][196];
    __shared__ __align__(16) float xh2[64][132];
    __shared__ __align__(16) float xh3[64][68];
    const int tid = threadIdx.x;
    const int r0 = blockIdx.x * 64;
    for (int i = tid; i < 64 * 64; i += 256) { int r = i >> 6, c = i & 63; xin[r][c] = gnn[(size_t)(r0 + r) * 64 + c]; }
    for (int i = tid; i < 64 * 128; i += 256) { int r = i >> 7, c = i & 127; xin[r][64 + c] = rnn[(size_t)(r0 + r) * 128 + c]; }
    __syncthreads();
    const int wv = tid >> 6, ln = tid & 63, wr = wv * 16;
    const float rs = rsqrtf(1.0f + 1e-5f);
    // fc1: wave owns 16 rows; lane owns cols {2*ln, 2*ln+1}
    float a[16][2];
    float b0 = fc1b[2 * ln], b1 = fc1b[2 * ln + 1];
#pragma unroll
    for (int r = 0; r < 16; ++r) { a[r][0] = b0; a[r][1] = b1; }
    for (int k = 0; k < 192; ++k) {
        v2 w = *(const v2*)&fc1w[k * 128 + 2 * ln];
#pragma unroll
        for (int r = 0; r < 16; ++r) { float x = xin[wr + r][k]; a[r][0] += x * w[0]; a[r][1] += x * w[1]; }
    }
    float s0 = fbng[2 * ln] * rs, s1 = fbng[2 * ln + 1] * rs;
    float bb0 = fbnb[2 * ln], bb1 = fbnb[2 * ln + 1];
#pragma unroll
    for (int r = 0; r < 16; ++r) {
        v2 h;
        h[0] = fmaxf(a[r][0] * s0 + bb0, 0.f);
        h[1] = fmaxf(a[r][1] * s1 + bb1, 0.f);
        *(v2*)&xh2[wr + r][2 * ln] = h;
    }
    __syncthreads();
    // fc2: wave owns 16 rows; lane owns 1 col
    float a2[16];
    float b2 = fc2b[ln];
#pragma unroll
    for (int r = 0; r < 16; ++r) a2[r] = b2;
    for (int k = 0; k < 128; ++k) {
        float w = fc2w[k * 64 + ln];
#pragma unroll
        for (int r = 0; r < 16; ++r) a2[r] += xh2[wr + r][k] * w;
    }
#pragma unroll
    for (int r = 0; r < 16; ++r) xh3[wr + r][ln] = fmaxf(a2[r], 0.f);
    __syncthreads();
    if (ln < 10) {
#pragma unroll
        for (int r = 0; r < 16; ++r) {
            float a3 = outb[ln];
#pragma unroll 8
            for (int k = 0; k < 64; ++k) a3 += xh3[wr + r][k] * outw[k * 10 + ln];
            out[(size_t)(r0 + wr + r) * 10 + ln] = a3;
        }
    }
}

extern "C" void kernel_launch(void* const* d_in, const int* in_sizes, int n_in,
                              void* d_out, int out_size, void* d_ws, size_t ws_size,
                              hipStream_t stream) {
    const float* dyn  = (const float*)d_in[0];
    const float* xs_  = (const float*)d_in[1];
    const int*   ei   = (const int*)d_in[2];
    const float* g1w  = (const float*)d_in[3];
    const float* g1b  = (const float*)d_in[4];
    const float* g2w  = (const float*)d_in[5];
    const float* g2b  = (const float*)d_in[6];
    const float* bn1g = (const float*)d_in[7];
    const float* bn1b = (const float*)d_in[8];
    const float* bn2g = (const float*)d_in[9];
    const float* bn2b = (const float*)d_in[10];
    const float* wih0 = (const float*)d_in[11];
    const float* whh0 = (const float*)d_in[12];
    const float* bih0 = (const float*)d_in[13];
    const float* bhh0 = (const float*)d_in[14];
    const float* wih1 = (const float*)d_in[15];
    const float* whh1 = (const float*)d_in[16];
    const float* bih1 = (const float*)d_in[17];
    const float* bhh1 = (const float*)d_in[18];
    const float* fc1w = (const float*)d_in[19];
    const float* fc1b = (const float*)d_in[20];
    const float* fbng = (const float*)d_in[21];
    const float* fbnb = (const float*)d_in[22];
    const float* fc2w = (const float*)d_in[23];
    const float* fc2b = (const float*)d_in[24];
    const float* outw = (const float*)d_in[25];
    const float* outb = (const float*)d_in[26];
    float* out = (float*)d_out;

    char* ws = (char*)d_ws;
    _Float16* WB0h  = (_Float16*)(ws + 0);
    _Float16* TLg   = (_Float16*)(ws + 131072);
    _Float16* WB1   = (_Float16*)(ws + 147456);
    _Float16* dyn16 = (_Float16*)(ws + 409600);
    float* fbase = (float*)(ws + 8798208);
    float* bias = fbase;
    float* dis  = fbase + 1024;
    _Float16* hs  = (_Float16*)(fbase + 9216);   // 8192x64 f16 (1 MB)
    _Float16* hs2 = (_Float16*)(fbase + 533504); // 8192x64 f16 (1 MB)
    float* gnn  = fbase + 1057792;
    float* rnn  = fbase + 1582080;
    int* ibase   = (int*)(ws + 19320832);
    int* cnt     = ibase;
    int* cursor  = ibase + 8192;
    int* rowstart= ibase + 16384;
    int* srcidx  = ibase + 24592;

    const int* srcp = ei;
    const int* dstp = ei + NE;

    hipMemsetAsync(cnt, 0, 2 * 8192 * sizeof(int), stream);  // cnt + cursor
    k_prep_all<<<7972, 256, 0, stream>>>(dyn, wih0, whh0, bih0, bhh0, wih1, whh1, bih1, bhh1,
                                         dstp, xs_, g1w, dyn16, WB0h, TLg, WB1, bias, cnt, hs);
    k_scan<<<1, 1024, 0, stream>>>(cnt, rowstart, dis);
    k_fill<<<1024, 256, 0, stream>>>(srcp, dstp, rowstart, cursor, srcidx);
    k_gather_gemm<<<2048, 256, 0, stream>>>(hs, srcidx, rowstart, dis, g1b, bn1g, bn1b, g2w, hs2);
    k_gather<<<2048, 256, 0, stream>>>(hs2, srcidx, rowstart, dis, g2b, bn2g, bn2b, gnn);
    k_lstm<<<256, 512, 0, stream>>>(dyn16, WB0h, TLg, WB1, bias, rnn);
    k_head<<<128, 256, 0, stream>>>(gnn, rnn, fc1w, fc1b, fbng, fbnb, fc2w, fc2b, outw, outb, out);
}

// Round 11
// 290.066 us; speedup vs baseline: 1.0601x; 1.0601x over previous
//
#include <hip/hip_runtime.h>
#include <hip/hip_bf16.h>

#define NN 8192
#define NE 262144

typedef float v2 __attribute__((ext_vector_type(2)));
typedef float v4 __attribute__((ext_vector_type(4)));
typedef float f4 __attribute__((ext_vector_type(4)));
typedef _Float16 h8 __attribute__((ext_vector_type(8)));
typedef _Float16 h4 __attribute__((ext_vector_type(4)));

__device__ __forceinline__ float rcp_(float x) { return __builtin_amdgcn_rcpf(x); }
__device__ __forceinline__ float sigm(float x) { return rcp_(1.0f + __expf(-x)); }
__device__ __forceinline__ float tanh_(float x) { return 1.0f - 2.0f * rcp_(__expf(2.0f * x) + 1.0f); }

// ---------------- merged prep: LSTM weights + dyn->f16 + degree count + GCN gemm1 ----------------
__global__ void k_prep_all(const float* __restrict__ dyn,
                           const float* __restrict__ wih0, const float* __restrict__ whh0,
                           const float* __restrict__ bih0, const float* __restrict__ bhh0,
                           const float* __restrict__ wih1, const float* __restrict__ whh1,
                           const float* __restrict__ bih1, const float* __restrict__ bhh1,
                           const int* __restrict__ dst,
                           const float* __restrict__ xs_, const float* __restrict__ g1w,
                           _Float16* __restrict__ dyn16, _Float16* __restrict__ WB0h,
                           _Float16* __restrict__ TLg, _Float16* __restrict__ WB1,
                           float* __restrict__ bias, int* __restrict__ cnt,
                           float* __restrict__ hs_raw) {
    int b = blockIdx.x, tid = threadIdx.x;
    if (b < 4096) {
        int i = b * 256 + tid;
        f4 v = *(const f4*)(dyn + (size_t)i * 4);
        h4 o = {(_Float16)v[0], (_Float16)v[1], (_Float16)v[2], (_Float16)v[3]};
        *(h4*)(dyn16 + (size_t)i * 4) = o;
    } else if (b < 4900) {
        int i = (b - 4096) * 256 + tid;  // < 205824 exactly
        if (i < 65536) {
            int idx = i & 7, col = (i >> 3) & 511, kgq = (i >> 12) & 3, kt = i >> 14;
            int kh = kt * 32 + kgq * 8 + idx;
            WB0h[i] = (_Float16)whh0[col * 128 + kh];
        } else if (i < 73728) {
            int m = i - 65536;
            int kd = m & 15, g = m >> 4;
            TLg[m] = (_Float16)wih0[g * 16 + kd];
        } else if (i < 204800) {
            int m = i - 73728;
            int kt = m >> 14, rem = m & 16383, g = rem >> 5, kk = rem & 31, k = kt * 32 + kk;
            WB1[m] = (_Float16)((k < 128) ? wih1[g * 128 + k] : whh1[g * 128 + (k - 128)]);
        } else {
            int g = i - 204800;
            bias[g] = (g < 512) ? (bih0[g] + bhh0[g]) : (bih1[g - 512] + bhh1[g - 512]);
        }
    } else if (b < 5924) {
        int e = (b - 4900) * 256 + tid;
        if (e < NE) atomicAdd(&cnt[dst[e]], 1);
    } else {
        int wv = tid >> 6, ln = tid & 63;
        int row = (b - 5924) * 4 + wv;
        const float* xp = xs_ + (size_t)row * 128;
        float a = 0.f;
#pragma unroll 4
        for (int k = 0; k < 128; ++k) a += xp[k] * g1w[k * 64 + ln];
        hs_raw[(size_t)row * 64 + ln] = a;
    }
}

// ---------------- GCN: CSR build ----------------
__global__ __launch_bounds__(1024) void k_scan(const int* __restrict__ cnt, int* __restrict__ rowstart,
                                               float* __restrict__ dis) {
    __shared__ int part[1024];
    int t = threadIdx.x;
    int base = t * 8, s = 0, loc[8];
#pragma unroll
    for (int i = 0; i < 8; ++i) { loc[i] = s; s += cnt[base + i]; }
    part[t] = s;
    __syncthreads();
    for (int off = 1; off < 1024; off <<= 1) {
        int v = part[t];
        int add = (t >= off) ? part[t - off] : 0;
        __syncthreads();
        part[t] = v + add;
        __syncthreads();
    }
    int pre = (t == 0) ? 0 : part[t - 1];
#pragma unroll
    for (int i = 0; i < 8; ++i) {
        rowstart[base + i] = pre + loc[i];
        dis[base + i] = rsqrtf((float)(cnt[base + i] + 1));
    }
    if (t == 1023) rowstart[8192] = NE;
}
__global__ void k_fill(const int* __restrict__ src, const int* __restrict__ dst,
                       const int* __restrict__ rowstart, int* __restrict__ cursor,
                       int* __restrict__ srcidx) {
    int e = blockIdx.x * 256 + threadIdx.x;
    if (e < NE) {
        int d = dst[e];
        int pos = rowstart[d] + atomicAdd(&cursor[d], 1);
        srcidx[pos] = src[e];
    }
}
// gather layer1 (dis per-source) + BN/ReLU + fused layer-2 GEMM -> hs2 RAW
__global__ __launch_bounds__(256) void k_gather_gemm(const float* __restrict__ hs, const int* __restrict__ srcidx,
                                                     const int* __restrict__ rowstart, const float* __restrict__ dis,
                                                     const float* __restrict__ gb, const float* __restrict__ bng,
                                                     const float* __restrict__ bnb, const float* __restrict__ g2w,
                                                     float* __restrict__ hs2) {
    int ln = threadIdx.x & 63;
    int d = (blockIdx.x * 256 + threadIdx.x) >> 6;
    float dd = dis[d];
    float acc = hs[(size_t)d * 64 + ln] * dd;
    int b = rowstart[d], e = rowstart[d + 1];
    int i = b;
    for (; i + 4 <= e; i += 4) {
        int s0 = srcidx[i], s1 = srcidx[i + 1], s2 = srcidx[i + 2], s3 = srcidx[i + 3];
        acc += hs[(size_t)s0 * 64 + ln] * dis[s0];
        acc += hs[(size_t)s1 * 64 + ln] * dis[s1];
        acc += hs[(size_t)s2 * 64 + ln] * dis[s2];
        acc += hs[(size_t)s3 * 64 + ln] * dis[s3];
    }
    for (; i < e; ++i) { int s = srcidx[i]; acc += hs[(size_t)s * 64 + ln] * dis[s]; }
    float rs = rsqrtf(1.0f + 1e-5f);
    float y = acc * dd + gb[ln];
    y = fmaxf(y * (bng[ln] * rs) + bnb[ln], 0.f);
    float a2 = 0.f;
#pragma unroll 8
    for (int k = 0; k < 64; ++k) a2 += __shfl(y, k, 64) * g2w[k * 64 + ln];
    hs2[(size_t)d * 64 + ln] = a2;
}
__global__ __launch_bounds__(256) void k_gather(const float* __restrict__ hs, const int* __restrict__ srcidx,
                                                const int* __restrict__ rowstart, const float* __restrict__ dis,
                                                const float* __restrict__ gb, const float* __restrict__ bng,
                                                const float* __restrict__ bnb, float* __restrict__ out) {
    int ln = threadIdx.x & 63;
    int d = (blockIdx.x * 256 + threadIdx.x) >> 6;
    float dd = dis[d];
    float acc = hs[(size_t)d * 64 + ln] * dd;
    int b = rowstart[d], e = rowstart[d + 1];
    int i = b;
    for (; i + 4 <= e; i += 4) {
        int s0 = srcidx[i], s1 = srcidx[i + 1], s2 = srcidx[i + 2], s3 = srcidx[i + 3];
        acc += hs[(size_t)s0 * 64 + ln] * dis[s0];
        acc += hs[(size_t)s1 * 64 + ln] * dis[s1];
        acc += hs[(size_t)s2 * 64 + ln] * dis[s2];
        acc += hs[(size_t)s3 * 64 + ln] * dis[s3];
    }
    for (; i < e; ++i) { int s = srcidx[i]; acc += hs[(size_t)s * 64 + ln] * dis[s]; }
    float rs = rsqrtf(1.0f + 1e-5f);
    float v = acc * dd + gb[ln];
    v = v * (bng[ln] * rs) + bnb[ln];
    out[(size_t)d * 64 + ln] = fmaxf(v, 0.f);
}

// ---------------- fused 2-layer LSTM: EXACT round-5 form (198 us measured) ----------------
__device__ __forceinline__ h8 ldx(const _Float16* xs, int buf, int row, int chunk) {
    return *(const h8*)((const char*)xs + buf * 16384 + row * 512 + ((chunk ^ (row & 7)) << 4));
}
__device__ __forceinline__ void wrx(_Float16* xs, int buf, int row, int col, _Float16 v) {
    *(_Float16*)((char*)xs + buf * 16384 + row * 512 + ((((col >> 3) ^ (row & 7))) << 4) + (col & 7) * 2) = v;
}

__global__ __launch_bounds__(512, 2) void k_lstm(const _Float16* __restrict__ dyn16,
                                                 const _Float16* __restrict__ WB0h,
                                                 const _Float16* __restrict__ TLg,
                                                 const _Float16* __restrict__ WB1,
                                                 const float* __restrict__ bias,
                                                 float* __restrict__ rnn) {
    __shared__ __align__(16) _Float16 wb0[65536];  // W_hh0, 128 KB
    __shared__ __align__(16) _Float16 xs[16384];   // 2 bufs x 32 rows x [h0|h1], swizzled

    const int tid = threadIdx.x;
    const int wv = tid >> 6, ln = tid & 63;
    const int lr = ln & 15, kg = ln >> 4;
    const int j = wv * 16 + lr;
    const int row0 = blockIdx.x * 32;

    for (int i = tid; i < 8192; i += 512) ((v4*)wb0)[i] = ((const v4*)WB0h)[i];
    for (int i = tid; i < 16384; i += 512) xs[i] = (_Float16)0.f;

    h8 b1r[8][4];
#pragma unroll
    for (int kt = 0; kt < 8; ++kt)
#pragma unroll
        for (int q = 0; q < 4; ++q)
            b1r[kt][q] = *(const h8*)(WB1 + (size_t)kt * 16384 + (q * 128 + j) * 32 + kg * 8);
    h8 bt[4];
#pragma unroll
    for (int q = 0; q < 4; ++q)
        bt[q] = *(const h8*)(TLg + (q * 128 + j) * 16 + (kg & 1) * 8);

    float b0q[4], b1q[4];
#pragma unroll
    for (int q = 0; q < 4; ++q) { b0q[q] = bias[q * 128 + j]; b1q[q] = bias[512 + q * 128 + j]; }
    float c0[2][4], c1[2][4];
#pragma unroll
    for (int mt = 0; mt < 2; ++mt)
#pragma unroll
        for (int r = 0; r < 4; ++r) { c0[mt][r] = 0.f; c1[mt][r] = 0.f; }

    h8 dreg[2];
#pragma unroll
    for (int mt = 0; mt < 2; ++mt)
#pragma unroll
        for (int e = 0; e < 8; ++e) dreg[mt][e] = (_Float16)0.f;
    if (kg < 2) {
#pragma unroll
        for (int mt = 0; mt < 2; ++mt)
            dreg[mt] = *(const h8*)(dyn16 + (size_t)(row0 + mt * 16 + lr) * 512 + (kg & 1) * 8);
    }
    __syncthreads();  // wb0 + xs zero init visible

    // ===== prologue: step 0, layer 0 (h0(-1)=0 -> only dyn tail) =====
    {
        f4 acc[2][4];
#pragma unroll
        for (int q = 0; q < 4; ++q) { f4 z = {b0q[q], b0q[q], b0q[q], b0q[q]}; acc[0][q] = z; acc[1][q] = z; }
#pragma unroll
        for (int q = 0; q < 4; ++q) {
            acc[0][q] = __builtin_amdgcn_mfma_f32_16x16x32_f16(dreg[0], bt[q], acc[0][q], 0, 0, 0);
            acc[1][q] = __builtin_amdgcn_mfma_f32_16x16x32_f16(dreg[1], bt[q], acc[1][q], 0, 0, 0);
        }
#pragma unroll
        for (int mt = 0; mt < 2; ++mt)
#pragma unroll
            for (int r = 0; r < 4; ++r) {
                float iv = acc[mt][0][r], fv = acc[mt][1][r], gv = acc[mt][2][r], ov = acc[mt][3][r];
                float c = sigm(fv) * c0[mt][r] + sigm(iv) * tanh_(gv);
                c0[mt][r] = c;
                wrx(xs, 0, mt * 16 + kg * 4 + r, j, (_Float16)(sigm(ov) * tanh_(c)));
            }
        if (kg < 2) {  // dreg <- dyn(1)
#pragma unroll
            for (int mt = 0; mt < 2; ++mt)
                dreg[mt] = *(const h8*)(dyn16 + (size_t)(row0 + mt * 16 + lr) * 512 + 16 + (kg & 1) * 8);
        }
    }

#pragma unroll 1
    for (int i = 0; i < 31; ++i) {
        const int cur = i & 1, old = cur ^ 1;
        __syncthreads();  // h0(i) visible
        f4 acc[2][4];
        // ===== G1(i): K=256 = [h0(i) buf cur | h1(i-1) buf old] =====
#pragma unroll
        for (int q = 0; q < 4; ++q) { f4 z = {b1q[q], b1q[q], b1q[q], b1q[q]}; acc[0][q] = z; acc[1][q] = z; }
#pragma unroll
        for (int kt = 0; kt < 8; ++kt) {
            const int bufA = (kt < 4) ? cur : old;
            const int ch = (kt < 4) ? (kt * 4 + kg) : (16 + (kt - 4) * 4 + kg);
            h8 a0 = ldx(xs, bufA, lr, ch);
            h8 a1 = ldx(xs, bufA, 16 + lr, ch);
#pragma unroll
            for (int q = 0; q < 4; ++q) {
                acc[0][q] = __builtin_amdgcn_mfma_f32_16x16x32_f16(a0, b1r[kt][q], acc[0][q], 0, 0, 0);
                acc[1][q] = __builtin_amdgcn_mfma_f32_16x16x32_f16(a1, b1r[kt][q], acc[1][q], 0, 0, 0);
            }
        }
        // ===== EW1(i) -> h1(i) into buf cur =====
#pragma unroll
        for (int mt = 0; mt < 2; ++mt)
#pragma unroll
            for (int r = 0; r < 4; ++r) {
                float iv = acc[mt][0][r], fv = acc[mt][1][r], gv = acc[mt][2][r], ov = acc[mt][3][r];
                float c = sigm(fv) * c1[mt][r] + sigm(iv) * tanh_(gv);
                c1[mt][r] = c;
                wrx(xs, cur, mt * 16 + kg * 4 + r, 128 + j, (_Float16)(sigm(ov) * tanh_(c)));
            }
        // ===== G0(i+1): K = [h0(i) buf cur 128 | dyn(i+1) 16 | pad 16] =====
#pragma unroll
        for (int q = 0; q < 4; ++q) { f4 z = {b0q[q], b0q[q], b0q[q], b0q[q]}; acc[0][q] = z; acc[1][q] = z; }
#pragma unroll
        for (int kt = 0; kt < 4; ++kt) {
            h8 a0 = ldx(xs, cur, lr, kt * 4 + kg);
            h8 a1 = ldx(xs, cur, 16 + lr, kt * 4 + kg);
            h8 bq[4];
#pragma unroll
            for (int q = 0; q < 4; ++q)
                bq[q] = *(const h8*)(wb0 + (size_t)(((kt * 4 + kg) * 512 + q * 128 + j) * 8));
#pragma unroll
            for (int q = 0; q < 4; ++q) {
                acc[0][q] = __builtin_amdgcn_mfma_f32_16x16x32_f16(a0, bq[q], acc[0][q], 0, 0, 0);
                acc[1][q] = __builtin_amdgcn_mfma_f32_16x16x32_f16(a1, bq[q], acc[1][q], 0, 0, 0);
            }
        }
#pragma unroll
        for (int q = 0; q < 4; ++q) {
            acc[0][q] = __builtin_amdgcn_mfma_f32_16x16x32_f16(dreg[0], bt[q], acc[0][q], 0, 0, 0);
            acc[1][q] = __builtin_amdgcn_mfma_f32_16x16x32_f16(dreg[1], bt[q], acc[1][q], 0, 0, 0);
        }
        // ===== EW0(i+1) -> h0(i+1) into buf old =====
#pragma unroll
        for (int mt = 0; mt < 2; ++mt)
#pragma unroll
            for (int r = 0; r < 4; ++r) {
                float iv = acc[mt][0][r], fv = acc[mt][1][r], gv = acc[mt][2][r], ov = acc[mt][3][r];
                float c = sigm(fv) * c0[mt][r] + sigm(iv) * tanh_(gv);
                c0[mt][r] = c;
                wrx(xs, old, mt * 16 + kg * 4 + r, j, (_Float16)(sigm(ov) * tanh_(c)));
            }
        if (i < 30 && kg < 2) {  // prefetch dyn(i+2) (R5 placement)
#pragma unroll
            for (int mt = 0; mt < 2; ++mt)
                dreg[mt] = *(const h8*)(dyn16 + (size_t)(row0 + mt * 16 + lr) * 512 + (i + 2) * 16 + (kg & 1) * 8);
        }
    }
    __syncthreads();  // h0(31) visible
    // ===== epilogue: G1(31) + EW1(31) -> rnn =====
    {
        const int cur = 1, old = 0;
        f4 acc[2][4];
#pragma unroll
        for (int q = 0; q < 4; ++q) { f4 z = {b1q[q], b1q[q], b1q[q], b1q[q]}; acc[0][q] = z; acc[1][q] = z; }
#pragma unroll
        for (int kt = 0; kt < 8; ++kt) {
            const int bufA = (kt < 4) ? cur : old;
            const int ch = (kt < 4) ? (kt * 4 + kg) : (16 + (kt - 4) * 4 + kg);
            h8 a0 = ldx(xs, bufA, lr, ch);
            h8 a1 = ldx(xs, bufA, 16 + lr, ch);
#pragma unroll
            for (int q = 0; q < 4; ++q) {
                acc[0][q] = __builtin_amdgcn_mfma_f32_16x16x32_f16(a0, b1r[kt][q], acc[0][q], 0, 0, 0);
                acc[1][q] = __builtin_amdgcn_mfma_f32_16x16x32_f16(a1, b1r[kt][q], acc[1][q], 0, 0, 0);
            }
        }
#pragma unroll
        for (int mt = 0; mt < 2; ++mt)
#pragma unroll
            for (int r = 0; r < 4; ++r) {
                float iv = acc[mt][0][r], fv = acc[mt][1][r], gv = acc[mt][2][r], ov = acc[mt][3][r];
                float c = sigm(fv) * c1[mt][r] + sigm(iv) * tanh_(gv);
                float h = sigm(ov) * tanh_(c);
                rnn[(size_t)(row0 + mt * 16 + kg * 4 + r) * 128 + j] = h;
            }
    }
}

// ---------------- head: 1024 blocks x 8 rows (max latency hiding; weights L2-resident) ----------------
__global__ __launch_bounds__(256) void k_head(const float* __restrict__ gnn, const float* __restrict__ rnn,
                                              const float* __restrict__ fc1w, const float* __restrict__ fc1b,
                                              const float* __restrict__ fbng, const float* __restrict__ fbnb,
                                              const float* __restrict__ fc2w, const float* __restrict__ fc2b,
                                              const float* __restrict__ outw, const float* __restrict__ outb,
                                              float* __restrict__ out) {
    __shared__ __align__(16) float xin[8][196];
    __shared__ __align__(16) float xh2[8][132];
    __shared__ __align__(16) float xh3[8][68];
    const int tid = threadIdx.x;
    const int r0 = blockIdx.x * 8;
    for (int i = tid; i < 8 * 64; i += 256) { int r = i >> 6, c = i & 63; xin[r][c] = gnn[(size_t)(r0 + r) * 64 + c]; }
    for (int i = tid; i < 8 * 128; i += 256) { int r = i >> 7, c = i & 127; xin[r][64 + c] = rnn[(size_t)(r0 + r) * 128 + c]; }
    __syncthreads();
    const int wv = tid >> 6, ln = tid & 63, wr = wv * 2;
    const float rs = rsqrtf(1.0f + 1e-5f);
    float a[2][2];
    float b0 = fc1b[2 * ln], b1 = fc1b[2 * ln + 1];
#pragma unroll
    for (int r = 0; r < 2; ++r) { a[r][0] = b0; a[r][1] = b1; }
#pragma unroll 4
    for (int k = 0; k < 192; ++k) {
        v2 w = *(const v2*)&fc1w[k * 128 + 2 * ln];
#pragma unroll
        for (int r = 0; r < 2; ++r) { float x = xin[wr + r][k]; a[r][0] += x * w[0]; a[r][1] += x * w[1]; }
    }
    float s0 = fbng[2 * ln] * rs, s1 = fbng[2 * ln + 1] * rs;
    float bb0 = fbnb[2 * ln], bb1 = fbnb[2 * ln + 1];
#pragma unroll
    for (int r = 0; r < 2; ++r) {
        v2 h;
        h[0] = fmaxf(a[r][0] * s0 + bb0, 0.f);
        h[1] = fmaxf(a[r][1] * s1 + bb1, 0.f);
        *(v2*)&xh2[wr + r][2 * ln] = h;
    }
    __syncthreads();
    float a2[2];
    float b2 = fc2b[ln];
#pragma unroll
    for (int r = 0; r < 2; ++r) a2[r] = b2;
#pragma unroll 4
    for (int k = 0; k < 128; ++k) {
        float w = fc2w[k * 64 + ln];
#pragma unroll
        for (int r = 0; r < 2; ++r) a2[r] += xh2[wr + r][k] * w;
    }
#pragma unroll
    for (int r = 0; r < 2; ++r) xh3[wr + r][ln] = fmaxf(a2[r], 0.f);
    __syncthreads();
    if (ln < 10) {
#pragma unroll
        for (int r = 0; r < 2; ++r) {
            float a3 = outb[ln];
#pragma unroll 8
            for (int k = 0; k < 64; ++k) a3 += xh3[wr + r][k] * outw[k * 10 + ln];
            out[(size_t)(r0 + wr + r) * 10 + ln] = a3;
        }
    }
}

extern "C" void kernel_launch(void* const* d_in, const int* in_sizes, int n_in,
                              void* d_out, int out_size, void* d_ws, size_t ws_size,
                              hipStream_t stream) {
    const float* dyn  = (const float*)d_in[0];
    const float* xs_  = (const float*)d_in[1];
    const int*   ei   = (const int*)d_in[2];
    const float* g1w  = (const float*)d_in[3];
    const float* g1b  = (const float*)d_in[4];
    const float* g2w  = (const float*)d_in[5];
    const float* g2b  = (const float*)d_in[6];
    const float* bn1g = (const float*)d_in[7];
    const float* bn1b = (const float*)d_in[8];
    const float* bn2g = (const float*)d_in[9];
    const float* bn2b = (const float*)d_in[10];
    const float* wih0 = (const float*)d_in[11];
    const float* whh0 = (const float*)d_in[12];
    const float* bih0 = (const float*)d_in[13];
    const float* bhh0 = (const float*)d_in[14];
    const float* wih1 = (const float*)d_in[15];
    const float* whh1 = (const float*)d_in[16];
    const float* bih1 = (const float*)d_in[17];
    const float* bhh1 = (const float*)d_in[18];
    const float* fc1w = (const float*)d_in[19];
    const float* fc1b = (const float*)d_in[20];
    const float* fbng = (const float*)d_in[21];
    const float* fbnb = (const float*)d_in[22];
    const float* fc2w = (const float*)d_in[23];
    const float* fc2b = (const float*)d_in[24];
    const float* outw = (const float*)d_in[25];
    const float* outb = (const float*)d_in[26];
    float* out = (float*)d_out;

    char* ws = (char*)d_ws;
    _Float16* WB0h  = (_Float16*)(ws + 0);
    _Float16* TLg   = (_Float16*)(ws + 131072);
    _Float16* WB1   = (_Float16*)(ws + 147456);
    _Float16* dyn16 = (_Float16*)(ws + 409600);
    float* fbase = (float*)(ws + 8798208);
    float* bias = fbase;
    float* dis  = fbase + 1024;
    float* hs   = fbase + 9216;
    float* hs2  = fbase + 533504;
    float* gnn  = fbase + 1057792;
    float* rnn  = fbase + 1582080;
    int* ibase   = (int*)(ws + 19320832);
    int* cnt     = ibase;
    int* cursor  = ibase + 8192;
    int* rowstart= ibase + 16384;
    int* srcidx  = ibase + 24592;

    const int* srcp = ei;
    const int* dstp = ei + NE;

    hipMemsetAsync(cnt, 0, 2 * 8192 * sizeof(int), stream);  // cnt + cursor
    k_prep_all<<<7972, 256, 0, stream>>>(dyn, wih0, whh0, bih0, bhh0, wih1, whh1, bih1, bhh1,
                                         dstp, xs_, g1w, dyn16, WB0h, TLg, WB1, bias, cnt, hs);
    k_scan<<<1, 1024, 0, stream>>>(cnt, rowstart, dis);
    k_fill<<<1024, 256, 0, stream>>>(srcp, dstp, rowstart, cursor, srcidx);
    k_gather_gemm<<<2048, 256, 0, stream>>>(hs, srcidx, rowstart, dis, g1b, bn1g, bn1b, g2w, hs2);
    k_gather<<<2048, 256, 0, stream>>>(hs2, srcidx, rowstart, dis, g2b, bn2g, bn2b, gnn);
    k_lstm<<<256, 512, 0, stream>>>(dyn16, WB0h, TLg, WB1, bias, rnn);
    k_head<<<1024, 256, 0, stream>>>(gnn, rnn, fc1w, fc1b, fbng, fbnb, fc2w, fc2b, outw, outb, out);
}

// Round 12
// 277.819 us; speedup vs baseline: 1.1068x; 1.0441x over previous
//
#include <hip/hip_runtime.h>
#include <hip/hip_bf16.h>

#define NN 8192
#define NE 262144

typedef float v2 __attribute__((ext_vector_type(2)));
typedef float v4 __attribute__((ext_vector_type(4)));
typedef float f4 __attribute__((ext_vector_type(4)));
typedef _Float16 h8 __attribute__((ext_vector_type(8)));
typedef _Float16 h4 __attribute__((ext_vector_type(4)));

__device__ __forceinline__ float rcp_(float x) { return __builtin_amdgcn_rcpf(x); }
__device__ __forceinline__ float sigm(float x) { return rcp_(1.0f + __expf(-x)); }
__device__ __forceinline__ float tanh_(float x) { return 1.0f - 2.0f * rcp_(__expf(2.0f * x) + 1.0f); }

// ---------------- merged prep: LSTM weights + dyn->f16 + degree count + GCN gemm1 ----------------
__global__ void k_prep_all(const float* __restrict__ dyn,
                           const float* __restrict__ wih0, const float* __restrict__ whh0,
                           const float* __restrict__ bih0, const float* __restrict__ bhh0,
                           const float* __restrict__ wih1, const float* __restrict__ whh1,
                           const float* __restrict__ bih1, const float* __restrict__ bhh1,
                           const int* __restrict__ dst,
                           const float* __restrict__ xs_, const float* __restrict__ g1w,
                           _Float16* __restrict__ dyn16, _Float16* __restrict__ WB0h,
                           _Float16* __restrict__ TLg, _Float16* __restrict__ WB1,
                           float* __restrict__ bias, int* __restrict__ cnt,
                           float* __restrict__ hs_raw) {
    int b = blockIdx.x, tid = threadIdx.x;
    if (b < 4096) {
        int i = b * 256 + tid;
        f4 v = *(const f4*)(dyn + (size_t)i * 4);
        h4 o = {(_Float16)v[0], (_Float16)v[1], (_Float16)v[2], (_Float16)v[3]};
        *(h4*)(dyn16 + (size_t)i * 4) = o;
    } else if (b < 4900) {
        int i = (b - 4096) * 256 + tid;  // < 205824 exactly
        if (i < 65536) {
            int idx = i & 7, col = (i >> 3) & 511, kgq = (i >> 12) & 3, kt = i >> 14;
            int kh = kt * 32 + kgq * 8 + idx;
            WB0h[i] = (_Float16)whh0[col * 128 + kh];
        } else if (i < 73728) {
            int m = i - 65536;
            int kd = m & 15, g = m >> 4;
            TLg[m] = (_Float16)wih0[g * 16 + kd];
        } else if (i < 204800) {
            int m = i - 73728;
            int kt = m >> 14, rem = m & 16383, g = rem >> 5, kk = rem & 31, k = kt * 32 + kk;
            WB1[m] = (_Float16)((k < 128) ? wih1[g * 128 + k] : whh1[g * 128 + (k - 128)]);
        } else {
            int g = i - 204800;
            bias[g] = (g < 512) ? (bih0[g] + bhh0[g]) : (bih1[g - 512] + bhh1[g - 512]);
        }
    } else if (b < 5924) {
        int e = (b - 4900) * 256 + tid;
        if (e < NE) atomicAdd(&cnt[dst[e]], 1);
    } else {
        int wv = tid >> 6, ln = tid & 63;
        int row = (b - 5924) * 4 + wv;
        const float* xp = xs_ + (size_t)row * 128;
        float a = 0.f;
#pragma unroll 4
        for (int k = 0; k < 128; ++k) a += xp[k] * g1w[k * 64 + ln];
        hs_raw[(size_t)row * 64 + ln] = a;
    }
}

// ---------------- GCN: CSR build ----------------
__global__ __launch_bounds__(1024) void k_scan(const int* __restrict__ cnt, int* __restrict__ rowstart,
                                               float* __restrict__ dis) {
    __shared__ int part[1024];
    int t = threadIdx.x;
    int base = t * 8, s = 0, loc[8];
#pragma unroll
    for (int i = 0; i < 8; ++i) { loc[i] = s; s += cnt[base + i]; }
    part[t] = s;
    __syncthreads();
    for (int off = 1; off < 1024; off <<= 1) {
        int v = part[t];
        int add = (t >= off) ? part[t - off] : 0;
        __syncthreads();
        part[t] = v + add;
        __syncthreads();
    }
    int pre = (t == 0) ? 0 : part[t - 1];
#pragma unroll
    for (int i = 0; i < 8; ++i) {
        rowstart[base + i] = pre + loc[i];
        dis[base + i] = rsqrtf((float)(cnt[base + i] + 1));
    }
    if (t == 1023) rowstart[8192] = NE;
}
__global__ void k_fill(const int* __restrict__ src, const int* __restrict__ dst,
                       const int* __restrict__ rowstart, int* __restrict__ cursor,
                       int* __restrict__ srcidx) {
    int e = blockIdx.x * 256 + threadIdx.x;
    if (e < NE) {
        int d = dst[e];
        int pos = rowstart[d] + atomicAdd(&cursor[d], 1);
        srcidx[pos] = src[e];
    }
}
// gather layer1 (dis per-source) + BN/ReLU + fused layer-2 GEMM -> hs2 RAW
__global__ __launch_bounds__(256) void k_gather_gemm(const float* __restrict__ hs, const int* __restrict__ srcidx,
                                                     const int* __restrict__ rowstart, const float* __restrict__ dis,
                                                     const float* __restrict__ gb, const float* __restrict__ bng,
                                                     const float* __restrict__ bnb, const float* __restrict__ g2w,
                                                     float* __restrict__ hs2) {
    int ln = threadIdx.x & 63;
    int d = (blockIdx.x * 256 + threadIdx.x) >> 6;
    float dd = dis[d];
    float acc = hs[(size_t)d * 64 + ln] * dd;
    int b = rowstart[d], e = rowstart[d + 1];
    int i = b;
    for (; i + 4 <= e; i += 4) {
        int s0 = srcidx[i], s1 = srcidx[i + 1], s2 = srcidx[i + 2], s3 = srcidx[i + 3];
        acc += hs[(size_t)s0 * 64 + ln] * dis[s0];
        acc += hs[(size_t)s1 * 64 + ln] * dis[s1];
        acc += hs[(size_t)s2 * 64 + ln] * dis[s2];
        acc += hs[(size_t)s3 * 64 + ln] * dis[s3];
    }
    for (; i < e; ++i) { int s = srcidx[i]; acc += hs[(size_t)s * 64 + ln] * dis[s]; }
    float rs = rsqrtf(1.0f + 1e-5f);
    float y = acc * dd + gb[ln];
    y = fmaxf(y * (bng[ln] * rs) + bnb[ln], 0.f);
    float a2 = 0.f;
#pragma unroll 8
    for (int k = 0; k < 64; ++k) a2 += __shfl(y, k, 64) * g2w[k * 64 + ln];
    hs2[(size_t)d * 64 + ln] = a2;
}
__global__ __launch_bounds__(256) void k_gather(const float* __restrict__ hs, const int* __restrict__ srcidx,
                                                const int* __restrict__ rowstart, const float* __restrict__ dis,
                                                const float* __restrict__ gb, const float* __restrict__ bng,
                                                const float* __restrict__ bnb, float* __restrict__ out) {
    int ln = threadIdx.x & 63;
    int d = (blockIdx.x * 256 + threadIdx.x) >> 6;
    float dd = dis[d];
    float acc = hs[(size_t)d * 64 + ln] * dd;
    int b = rowstart[d], e = rowstart[d + 1];
    int i = b;
    for (; i + 4 <= e; i += 4) {
        int s0 = srcidx[i], s1 = srcidx[i + 1], s2 = srcidx[i + 2], s3 = srcidx[i + 3];
        acc += hs[(size_t)s0 * 64 + ln] * dis[s0];
        acc += hs[(size_t)s1 * 64 + ln] * dis[s1];
        acc += hs[(size_t)s2 * 64 + ln] * dis[s2];
        acc += hs[(size_t)s3 * 64 + ln] * dis[s3];
    }
    for (; i < e; ++i) { int s = srcidx[i]; acc += hs[(size_t)s * 64 + ln] * dis[s]; }
    float rs = rsqrtf(1.0f + 1e-5f);
    float v = acc * dd + gb[ln];
    v = v * (bng[ln] * rs) + bnb[ln];
    out[(size_t)d * 64 + ln] = fmaxf(v, 0.f);
}

// ---------------- fused 2-layer LSTM: EXACT round-5 form (198 us measured) ----------------
__device__ __forceinline__ h8 ldx(const _Float16* xs, int buf, int row, int chunk) {
    return *(const h8*)((const char*)xs + buf * 16384 + row * 512 + ((chunk ^ (row & 7)) << 4));
}
__device__ __forceinline__ void wrx(_Float16* xs, int buf, int row, int col, _Float16 v) {
    *(_Float16*)((char*)xs + buf * 16384 + row * 512 + ((((col >> 3) ^ (row & 7))) << 4) + (col & 7) * 2) = v;
}

__global__ __launch_bounds__(512, 2) void k_lstm(const _Float16* __restrict__ dyn16,
                                                 const _Float16* __restrict__ WB0h,
                                                 const _Float16* __restrict__ TLg,
                                                 const _Float16* __restrict__ WB1,
                                                 const float* __restrict__ bias,
                                                 float* __restrict__ rnn) {
    __shared__ __align__(16) _Float16 wb0[65536];  // W_hh0, 128 KB
    __shared__ __align__(16) _Float16 xs[16384];   // 2 bufs x 32 rows x [h0|h1], swizzled

    const int tid = threadIdx.x;
    const int wv = tid >> 6, ln = tid & 63;
    const int lr = ln & 15, kg = ln >> 4;
    const int j = wv * 16 + lr;
    const int row0 = blockIdx.x * 32;

    for (int i = tid; i < 8192; i += 512) ((v4*)wb0)[i] = ((const v4*)WB0h)[i];
    for (int i = tid; i < 16384; i += 512) xs[i] = (_Float16)0.f;

    h8 b1r[8][4];
#pragma unroll
    for (int kt = 0; kt < 8; ++kt)
#pragma unroll
        for (int q = 0; q < 4; ++q)
            b1r[kt][q] = *(const h8*)(WB1 + (size_t)kt * 16384 + (q * 128 + j) * 32 + kg * 8);
    h8 bt[4];
#pragma unroll
    for (int q = 0; q < 4; ++q)
        bt[q] = *(const h8*)(TLg + (q * 128 + j) * 16 + (kg & 1) * 8);

    float b0q[4], b1q[4];
#pragma unroll
    for (int q = 0; q < 4; ++q) { b0q[q] = bias[q * 128 + j]; b1q[q] = bias[512 + q * 128 + j]; }
    float c0[2][4], c1[2][4];
#pragma unroll
    for (int mt = 0; mt < 2; ++mt)
#pragma unroll
        for (int r = 0; r < 4; ++r) { c0[mt][r] = 0.f; c1[mt][r] = 0.f; }

    h8 dreg[2];
#pragma unroll
    for (int mt = 0; mt < 2; ++mt)
#pragma unroll
        for (int e = 0; e < 8; ++e) dreg[mt][e] = (_Float16)0.f;
    if (kg < 2) {
#pragma unroll
        for (int mt = 0; mt < 2; ++mt)
            dreg[mt] = *(const h8*)(dyn16 + (size_t)(row0 + mt * 16 + lr) * 512 + (kg & 1) * 8);
    }
    __syncthreads();  // wb0 + xs zero init visible

    // ===== prologue: step 0, layer 0 (h0(-1)=0 -> only dyn tail) =====
    {
        f4 acc[2][4];
#pragma unroll
        for (int q = 0; q < 4; ++q) { f4 z = {b0q[q], b0q[q], b0q[q], b0q[q]}; acc[0][q] = z; acc[1][q] = z; }
#pragma unroll
        for (int q = 0; q < 4; ++q) {
            acc[0][q] = __builtin_amdgcn_mfma_f32_16x16x32_f16(dreg[0], bt[q], acc[0][q], 0, 0, 0);
            acc[1][q] = __builtin_amdgcn_mfma_f32_16x16x32_f16(dreg[1], bt[q], acc[1][q], 0, 0, 0);
        }
#pragma unroll
        for (int mt = 0; mt < 2; ++mt)
#pragma unroll
            for (int r = 0; r < 4; ++r) {
                float iv = acc[mt][0][r], fv = acc[mt][1][r], gv = acc[mt][2][r], ov = acc[mt][3][r];
                float c = sigm(fv) * c0[mt][r] + sigm(iv) * tanh_(gv);
                c0[mt][r] = c;
                wrx(xs, 0, mt * 16 + kg * 4 + r, j, (_Float16)(sigm(ov) * tanh_(c)));
            }
        if (kg < 2) {  // dreg <- dyn(1)
#pragma unroll
            for (int mt = 0; mt < 2; ++mt)
                dreg[mt] = *(const h8*)(dyn16 + (size_t)(row0 + mt * 16 + lr) * 512 + 16 + (kg & 1) * 8);
        }
    }

#pragma unroll 1
    for (int i = 0; i < 31; ++i) {
        const int cur = i & 1, old = cur ^ 1;
        __syncthreads();  // h0(i) visible
        f4 acc[2][4];
        // ===== G1(i): K=256 = [h0(i) buf cur | h1(i-1) buf old] =====
#pragma unroll
        for (int q = 0; q < 4; ++q) { f4 z = {b1q[q], b1q[q], b1q[q], b1q[q]}; acc[0][q] = z; acc[1][q] = z; }
#pragma unroll
        for (int kt = 0; kt < 8; ++kt) {
            const int bufA = (kt < 4) ? cur : old;
            const int ch = (kt < 4) ? (kt * 4 + kg) : (16 + (kt - 4) * 4 + kg);
            h8 a0 = ldx(xs, bufA, lr, ch);
            h8 a1 = ldx(xs, bufA, 16 + lr, ch);
#pragma unroll
            for (int q = 0; q < 4; ++q) {
                acc[0][q] = __builtin_amdgcn_mfma_f32_16x16x32_f16(a0, b1r[kt][q], acc[0][q], 0, 0, 0);
                acc[1][q] = __builtin_amdgcn_mfma_f32_16x16x32_f16(a1, b1r[kt][q], acc[1][q], 0, 0, 0);
            }
        }
        // ===== EW1(i) -> h1(i) into buf cur =====
#pragma unroll
        for (int mt = 0; mt < 2; ++mt)
#pragma unroll
            for (int r = 0; r < 4; ++r) {
                float iv = acc[mt][0][r], fv = acc[mt][1][r], gv = acc[mt][2][r], ov = acc[mt][3][r];
                float c = sigm(fv) * c1[mt][r] + sigm(iv) * tanh_(gv);
                c1[mt][r] = c;
                wrx(xs, cur, mt * 16 + kg * 4 + r, 128 + j, (_Float16)(sigm(ov) * tanh_(c)));
            }
        // ===== G0(i+1): K = [h0(i) buf cur 128 | dyn(i+1) 16 | pad 16] =====
#pragma unroll
        for (int q = 0; q < 4; ++q) { f4 z = {b0q[q], b0q[q], b0q[q], b0q[q]}; acc[0][q] = z; acc[1][q] = z; }
#pragma unroll
        for (int kt = 0; kt < 4; ++kt) {
            h8 a0 = ldx(xs, cur, lr, kt * 4 + kg);
            h8 a1 = ldx(xs, cur, 16 + lr, kt * 4 + kg);
            h8 bq[4];
#pragma unroll
            for (int q = 0; q < 4; ++q)
                bq[q] = *(const h8*)(wb0 + (size_t)(((kt * 4 + kg) * 512 + q * 128 + j) * 8));
#pragma unroll
            for (int q = 0; q < 4; ++q) {
                acc[0][q] = __builtin_amdgcn_mfma_f32_16x16x32_f16(a0, bq[q], acc[0][q], 0, 0, 0);
                acc[1][q] = __builtin_amdgcn_mfma_f32_16x16x32_f16(a1, bq[q], acc[1][q], 0, 0, 0);
            }
        }
#pragma unroll
        for (int q = 0; q < 4; ++q) {
            acc[0][q] = __builtin_amdgcn_mfma_f32_16x16x32_f16(dreg[0], bt[q], acc[0][q], 0, 0, 0);
            acc[1][q] = __builtin_amdgcn_mfma_f32_16x16x32_f16(dreg[1], bt[q], acc[1][q], 0, 0, 0);
        }
        // ===== EW0(i+1) -> h0(i+1) into buf old =====
#pragma unroll
        for (int mt = 0; mt < 2; ++mt)
#pragma unroll
            for (int r = 0; r < 4; ++r) {
                float iv = acc[mt][0][r], fv = acc[mt][1][r], gv = acc[mt][2][r], ov = acc[mt][3][r];
                float c = sigm(fv) * c0[mt][r] + sigm(iv) * tanh_(gv);
                c0[mt][r] = c;
                wrx(xs, old, mt * 16 + kg * 4 + r, j, (_Float16)(sigm(ov) * tanh_(c)));
            }
        if (i < 30 && kg < 2) {  // prefetch dyn(i+2) (R5 placement)
#pragma unroll
            for (int mt = 0; mt < 2; ++mt)
                dreg[mt] = *(const h8*)(dyn16 + (size_t)(row0 + mt * 16 + lr) * 512 + (i + 2) * 16 + (kg & 1) * 8);
        }
    }
    __syncthreads();  // h0(31) visible
    // ===== epilogue: G1(31) + EW1(31) -> rnn =====
    {
        const int cur = 1, old = 0;
        f4 acc[2][4];
#pragma unroll
        for (int q = 0; q < 4; ++q) { f4 z = {b1q[q], b1q[q], b1q[q], b1q[q]}; acc[0][q] = z; acc[1][q] = z; }
#pragma unroll
        for (int kt = 0; kt < 8; ++kt) {
            const int bufA = (kt < 4) ? cur : old;
            const int ch = (kt < 4) ? (kt * 4 + kg) : (16 + (kt - 4) * 4 + kg);
            h8 a0 = ldx(xs, bufA, lr, ch);
            h8 a1 = ldx(xs, bufA, 16 + lr, ch);
#pragma unroll
            for (int q = 0; q < 4; ++q) {
                acc[0][q] = __builtin_amdgcn_mfma_f32_16x16x32_f16(a0, b1r[kt][q], acc[0][q], 0, 0, 0);
                acc[1][q] = __builtin_amdgcn_mfma_f32_16x16x32_f16(a1, b1r[kt][q], acc[1][q], 0, 0, 0);
            }
        }
#pragma unroll
        for (int mt = 0; mt < 2; ++mt)
#pragma unroll
            for (int r = 0; r < 4; ++r) {
                float iv = acc[mt][0][r], fv = acc[mt][1][r], gv = acc[mt][2][r], ov = acc[mt][3][r];
                float c = sigm(fv) * c1[mt][r] + sigm(iv) * tanh_(gv);
                float h = sigm(ov) * tanh_(c);
                rnn[(size_t)(row0 + mt * 16 + kg * 4 + r) * 128 + j] = h;
            }
    }
}

// ---------------- head: 512 blocks x 16 rows (measured optimum) ----------------
__global__ __launch_bounds__(256) void k_head(const float* __restrict__ gnn, const float* __restrict__ rnn,
                                              const float* __restrict__ fc1w, const float* __restrict__ fc1b,
                                              const float* __restrict__ fbng, const float* __restrict__ fbnb,
                                              const float* __restrict__ fc2w, const float* __restrict__ fc2b,
                                              const float* __restrict__ outw, const float* __restrict__ outb,
                                              float* __restrict__ out) {
    __shared__ __align__(16) float xin[16][196];
    __shared__ __align__(16) float xh2[16][132];
    __shared__ __align__(16) float xh3[16][68];
    const int tid = threadIdx.x;
    const int r0 = blockIdx.x * 16;
    for (int i = tid; i < 16 * 64; i += 256) { int r = i >> 6, c = i & 63; xin[r][c] = gnn[(size_t)(r0 + r) * 64 + c]; }
    for (int i = tid; i < 16 * 128; i += 256) { int r = i >> 7, c = i & 127; xin[r][64 + c] = rnn[(size_t)(r0 + r) * 128 + c]; }
    __syncthreads();
    const int wv = tid >> 6, ln = tid & 63, wr = wv * 4;
    const float rs = rsqrtf(1.0f + 1e-5f);
    float a[4][2];
    float b0 = fc1b[2 * ln], b1 = fc1b[2 * ln + 1];
#pragma unroll
    for (int r = 0; r < 4; ++r) { a[r][0] = b0; a[r][1] = b1; }
    for (int k = 0; k < 192; ++k) {
        v2 w = *(const v2*)&fc1w[k * 128 + 2 * ln];
#pragma unroll
        for (int r = 0; r < 4; ++r) { float x = xin[wr + r][k]; a[r][0] += x * w[0]; a[r][1] += x * w[1]; }
    }
    float s0 = fbng[2 * ln] * rs, s1 = fbng[2 * ln + 1] * rs;
    float bb0 = fbnb[2 * ln], bb1 = fbnb[2 * ln + 1];
#pragma unroll
    for (int r = 0; r < 4; ++r) {
        v2 h;
        h[0] = fmaxf(a[r][0] * s0 + bb0, 0.f);
        h[1] = fmaxf(a[r][1] * s1 + bb1, 0.f);
        *(v2*)&xh2[wr + r][2 * ln] = h;
    }
    __syncthreads();
    float a2[4];
    float b2 = fc2b[ln];
#pragma unroll
    for (int r = 0; r < 4; ++r) a2[r] = b2;
    for (int k = 0; k < 128; ++k) {
        float w = fc2w[k * 64 + ln];
#pragma unroll
        for (int r = 0; r < 4; ++r) a2[r] += xh2[wr + r][k] * w;
    }
#pragma unroll
    for (int r = 0; r < 4; ++r) xh3[wr + r][ln] = fmaxf(a2[r], 0.f);
    __syncthreads();
    if (ln < 10) {
#pragma unroll
        for (int r = 0; r < 4; ++r) {
            float a3 = outb[ln];
#pragma unroll 8
            for (int k = 0; k < 64; ++k) a3 += xh3[wr + r][k] * outw[k * 10 + ln];
            out[(size_t)(r0 + wr + r) * 10 + ln] = a3;
        }
    }
}

extern "C" void kernel_launch(void* const* d_in, const int* in_sizes, int n_in,
                              void* d_out, int out_size, void* d_ws, size_t ws_size,
                              hipStream_t stream) {
    const float* dyn  = (const float*)d_in[0];
    const float* xs_  = (const float*)d_in[1];
    const int*   ei   = (const int*)d_in[2];
    const float* g1w  = (const float*)d_in[3];
    const float* g1b  = (const float*)d_in[4];
    const float* g2w  = (const float*)d_in[5];
    const float* g2b  = (const float*)d_in[6];
    const float* bn1g = (const float*)d_in[7];
    const float* bn1b = (const float*)d_in[8];
    const float* bn2g = (const float*)d_in[9];
    const float* bn2b = (const float*)d_in[10];
    const float* wih0 = (const float*)d_in[11];
    const float* whh0 = (const float*)d_in[12];
    const float* bih0 = (const float*)d_in[13];
    const float* bhh0 = (const float*)d_in[14];
    const float* wih1 = (const float*)d_in[15];
    const float* whh1 = (const float*)d_in[16];
    const float* bih1 = (const float*)d_in[17];
    const float* bhh1 = (const float*)d_in[18];
    const float* fc1w = (const float*)d_in[19];
    const float* fc1b = (const float*)d_in[20];
    const float* fbng = (const float*)d_in[21];
    const float* fbnb = (const float*)d_in[22];
    const float* fc2w = (const float*)d_in[23];
    const float* fc2b = (const float*)d_in[24];
    const float* outw = (const float*)d_in[25];
    const float* outb = (const float*)d_in[26];
    float* out = (float*)d_out;

    char* ws = (char*)d_ws;
    _Float16* WB0h  = (_Float16*)(ws + 0);
    _Float16* TLg   = (_Float16*)(ws + 131072);
    _Float16* WB1   = (_Float16*)(ws + 147456);
    _Float16* dyn16 = (_Float16*)(ws + 409600);
    float* fbase = (float*)(ws + 8798208);
    float* bias = fbase;
    float* dis  = fbase + 1024;
    float* hs   = fbase + 9216;
    float* hs2  = fbase + 533504;
    float* gnn  = fbase + 1057792;
    float* rnn  = fbase + 1582080;
    int* ibase   = (int*)(ws + 19320832);
    int* cnt     = ibase;
    int* cursor  = ibase + 8192;
    int* rowstart= ibase + 16384;
    int* srcidx  = ibase + 24592;

    const int* srcp = ei;
    const int* dstp = ei + NE;

    hipMemsetAsync(cnt, 0, 2 * 8192 * sizeof(int), stream);  // cnt + cursor
    k_prep_all<<<7972, 256, 0, stream>>>(dyn, wih0, whh0, bih0, bhh0, wih1, whh1, bih1, bhh1,
                                         dstp, xs_, g1w, dyn16, WB0h, TLg, WB1, bias, cnt, hs);
    k_scan<<<1, 1024, 0, stream>>>(cnt, rowstart, dis);
    k_fill<<<1024, 256, 0, stream>>>(srcp, dstp, rowstart, cursor, srcidx);
    k_gather_gemm<<<2048, 256, 0, stream>>>(hs, srcidx, rowstart, dis, g1b, bn1g, bn1b, g2w, hs2);
    k_gather<<<2048, 256, 0, stream>>>(hs2, srcidx, rowstart, dis, g2b, bn2g, bn2b, gnn);
    k_lstm<<<256, 512, 0, stream>>>(dyn16, WB0h, TLg, WB1, bias, rnn);
    k_head<<<512, 256, 0, stream>>>(gnn, rnn, fc1w, fc1b, fbng, fbnb, fc2w, fc2b, outw, outb, out);
}